// Round 2
// baseline (7776.702 us; speedup 1.0000x reference)
//
#include <hip/hip_runtime.h>
#include <hip/hip_bf16.h>
#include <math.h>

// MLA prefill, fp32 baseline with absorbed kv_b (decompressed K/V).
// B=2 S=1024 H=4096 N=64 NOPE=128 ROPE=64 V=128 KV_LORA=512 Q_LORA=1536 QK=192

#define SCALE_QK 0.07216878364870322f  // 192^-0.5

// ---------------------------------------------------------------------------
// GEMM: C[M,N] = A[M,K] @ B[N,K]^T   (row-major, K%16==0, M%128==0, N%8==0)
// ---------------------------------------------------------------------------
#define BM 128
#define BN 128
#define BK 16
#define LDT (BM + 4)

__global__ __launch_bounds__(256) void gemm_abt(
    const float* __restrict__ A, const float* __restrict__ B,
    float* __restrict__ C, int M, int N, int K)
{
    __shared__ float As[BK][LDT];
    __shared__ float Bs[BK][LDT];
    const int t  = threadIdx.x;
    const int tx = t & 15, ty = t >> 4;
    const int m0 = blockIdx.y * BM;
    const int n0 = blockIdx.x * BN;
    const int lrow = t >> 1;          // 0..127
    const int lk   = (t & 1) * 8;     // k-col base 0 or 8

    float acc[8][8];
#pragma unroll
    for (int i = 0; i < 8; ++i)
#pragma unroll
        for (int j = 0; j < 8; ++j) acc[i][j] = 0.f;

    const bool bvalid = (n0 + lrow) < N;

    for (int k0 = 0; k0 < K; k0 += BK) {
        {
            const float* ap = A + (size_t)(m0 + lrow) * K + k0 + lk;
            float4 a0 = *(const float4*)ap;
            float4 a1 = *(const float4*)(ap + 4);
            As[lk + 0][lrow] = a0.x; As[lk + 1][lrow] = a0.y;
            As[lk + 2][lrow] = a0.z; As[lk + 3][lrow] = a0.w;
            As[lk + 4][lrow] = a1.x; As[lk + 5][lrow] = a1.y;
            As[lk + 6][lrow] = a1.z; As[lk + 7][lrow] = a1.w;
            float4 b0 = make_float4(0.f, 0.f, 0.f, 0.f);
            float4 b1 = make_float4(0.f, 0.f, 0.f, 0.f);
            if (bvalid) {
                const float* bp = B + (size_t)(n0 + lrow) * K + k0 + lk;
                b0 = *(const float4*)bp;
                b1 = *(const float4*)(bp + 4);
            }
            Bs[lk + 0][lrow] = b0.x; Bs[lk + 1][lrow] = b0.y;
            Bs[lk + 2][lrow] = b0.z; Bs[lk + 3][lrow] = b0.w;
            Bs[lk + 4][lrow] = b1.x; Bs[lk + 5][lrow] = b1.y;
            Bs[lk + 6][lrow] = b1.z; Bs[lk + 7][lrow] = b1.w;
        }
        __syncthreads();
#pragma unroll
        for (int kk = 0; kk < BK; ++kk) {
            float4 a0 = *(const float4*)&As[kk][ty * 8];
            float4 a1 = *(const float4*)&As[kk][ty * 8 + 4];
            float4 b0 = *(const float4*)&Bs[kk][tx * 8];
            float4 b1 = *(const float4*)&Bs[kk][tx * 8 + 4];
            float av[8] = {a0.x, a0.y, a0.z, a0.w, a1.x, a1.y, a1.z, a1.w};
            float bv[8] = {b0.x, b0.y, b0.z, b0.w, b1.x, b1.y, b1.z, b1.w};
#pragma unroll
            for (int i = 0; i < 8; ++i)
#pragma unroll
                for (int j = 0; j < 8; ++j)
                    acc[i][j] = fmaf(av[i], bv[j], acc[i][j]);
        }
        __syncthreads();
    }

    if (n0 + tx * 8 < N) {
#pragma unroll
        for (int i = 0; i < 8; ++i) {
            float* cp = C + (size_t)(m0 + ty * 8 + i) * N + n0 + tx * 8;
            float4 c0 = make_float4(acc[i][0], acc[i][1], acc[i][2], acc[i][3]);
            float4 c1 = make_float4(acc[i][4], acc[i][5], acc[i][6], acc[i][7]);
            *(float4*)cp = c0;
            *(float4*)(cp + 4) = c1;
        }
    }
}

// ---------------------------------------------------------------------------
// RMSNorm in place over rows of length dim (here 1536)
// ---------------------------------------------------------------------------
__global__ __launch_bounds__(256) void rmsnorm_inplace(
    float* __restrict__ x, const float* __restrict__ w, int dim)
{
    __shared__ float red[4];
    const int row = blockIdx.x;
    float* xr = x + (size_t)row * dim;
    float ss = 0.f;
    for (int i = threadIdx.x; i < dim; i += 256) { float v = xr[i]; ss = fmaf(v, v, ss); }
#pragma unroll
    for (int off = 1; off < 64; off <<= 1) ss += __shfl_xor(ss, off, 64);
    const int lane = threadIdx.x & 63, wid = threadIdx.x >> 6;
    if (lane == 0) red[wid] = ss;
    __syncthreads();
    ss = red[0] + red[1] + red[2] + red[3];
    const float r = rsqrtf(ss / (float)dim + 1e-6f);
    for (int i = threadIdx.x; i < dim; i += 256) xr[i] = xr[i] * r * w[i];
}

// ---------------------------------------------------------------------------
// kv_a -> ckv (rmsnorm of first 512) + k_pe (rope of last 64)
// ---------------------------------------------------------------------------
__global__ __launch_bounds__(256) void kv_norm_rope(
    const float* __restrict__ kva, const float* __restrict__ w,
    const int* __restrict__ pos, const float* __restrict__ cosT,
    const float* __restrict__ sinT, float* __restrict__ ckv,
    float* __restrict__ kpe)
{
    __shared__ float red[4];
    const int row = blockIdx.x;
    const float* xr = kva + (size_t)row * 576;
    float ss = 0.f;
#pragma unroll
    for (int i = threadIdx.x; i < 512; i += 256) { float v = xr[i]; ss = fmaf(v, v, ss); }
#pragma unroll
    for (int off = 1; off < 64; off <<= 1) ss += __shfl_xor(ss, off, 64);
    const int lane = threadIdx.x & 63, wid = threadIdx.x >> 6;
    if (lane == 0) red[wid] = ss;
    __syncthreads();
    ss = red[0] + red[1] + red[2] + red[3];
    const float r = rsqrtf(ss / 512.f + 1e-6f);
#pragma unroll
    for (int i = threadIdx.x; i < 512; i += 256)
        ckv[(size_t)row * 512 + i] = xr[i] * r * w[i];
    if (threadIdx.x < 64) {
        const int d = threadIdx.x;
        const int p = pos[row];
        const float xd = xr[512 + d];
        const float xp = xr[512 + (d ^ 32)];
        const float rot = (d < 32) ? -xp : xp;
        kpe[(size_t)row * 64 + d] = xd * cosT[p * 64 + d] + rot * sinT[p * 64 + d];
    }
}

// ---------------------------------------------------------------------------
// RoPE on q_pe in place. q layout [2048][64 heads][192], pe = dims 128..191.
// One thread per (row, head, d); d and d^32 are in the same wave, and the
// loads precede the store in the single wave instruction stream -> race-free.
// ---------------------------------------------------------------------------
__global__ __launch_bounds__(256) void qpe_rope(
    float* __restrict__ q, const int* __restrict__ pos,
    const float* __restrict__ cosT, const float* __restrict__ sinT)
{
    const int idx = blockIdx.x * 256 + threadIdx.x;
    const int d = idx & 63;
    const int n = (idx >> 6) & 63;
    const int row = idx >> 12;
    const int p = pos[row];
    float* qp = q + (size_t)row * 12288 + n * 192 + 128;
    const float xd = qp[d];
    const float xp = qp[d ^ 32];
    const float rot = (d < 32) ? -xp : xp;
    qp[d] = xd * cosT[p * 64 + d] + rot * sinT[p * 64 + d];
}

// ---------------------------------------------------------------------------
// Flash attention, causal. TQ=TK=64, d_qk=192 (3 chunks of 64), d_v=128.
// Per block: (qb, head n, batch b). 256 threads = 16x16; scores 4x4/thread,
// PV out 4 rows x 8 dv/thread. LDS 52.2 KB: Qc|Kc|Ps, V overlays Qc+Kc.
// ---------------------------------------------------------------------------
#define TQ 64
#define TK 64
#define QSTR 68
#define VSTR 136

__global__ __launch_bounds__(256) void attn_kernel(
    const float* __restrict__ q, const float* __restrict__ kvup,
    const float* __restrict__ kpe, float* __restrict__ attno)
{
    __shared__ float smem[3 * 64 * QSTR];
    float* Qc = smem;
    float* Kc = smem + 64 * QSTR;
    float* Ps = smem + 2 * 64 * QSTR;
    float* Vs = smem;  // stride VSTR, overlays Qc+Kc exactly (64*136 = 2*64*68)

    const int t  = threadIdx.x;
    const int tx = t & 15, ty = t >> 4;
    const int qb = blockIdx.x;   // 0..15
    const int n  = blockIdx.y;   // 0..63
    const int b  = blockIdx.z;   // 0..1
    const int qs = qb * TQ;
    const size_t qrow0 = (size_t)b * 1024 + qs;

    const int lr = t >> 2;          // staging row 0..63
    const int c0 = (t & 3) * 4;     // staging col base

    float o[4][8];
#pragma unroll
    for (int i = 0; i < 4; ++i)
#pragma unroll
        for (int j = 0; j < 8; ++j) o[i][j] = 0.f;
    float mrow[4] = {-3e38f, -3e38f, -3e38f, -3e38f};
    float lsum[4] = {0.f, 0.f, 0.f, 0.f};

    for (int kt = 0; kt <= qb; ++kt) {
        const int ct = kt * TK;
        float s[4][4];
#pragma unroll
        for (int i = 0; i < 4; ++i)
#pragma unroll
            for (int j = 0; j < 4; ++j) s[i][j] = 0.f;

        for (int dc = 0; dc < 3; ++dc) {
            const int d0 = dc * 64;
            // stage Q chunk
            {
                const float* qp = q + (qrow0 + lr) * 12288 + n * 192 + d0;
#pragma unroll
                for (int k = 0; k < 4; ++k) {
                    const int c = c0 + 16 * k;
                    *(float4*)&Qc[lr * QSTR + c] = *(const float4*)(qp + c);
                }
            }
            // stage K chunk (nope from kvup, rope from kpe)
            {
                const float* kp = (dc < 2)
                    ? kvup + ((size_t)b * 1024 + ct + lr) * 16384 + n * 256 + d0
                    : kpe  + ((size_t)b * 1024 + ct + lr) * 64;
#pragma unroll
                for (int k = 0; k < 4; ++k) {
                    const int c = c0 + 16 * k;
                    *(float4*)&Kc[lr * QSTR + c] = *(const float4*)(kp + c);
                }
            }
            __syncthreads();
#pragma unroll
            for (int dd = 0; dd < 64; dd += 4) {
                float4 qa_[4], kb_[4];
#pragma unroll
                for (int i = 0; i < 4; ++i)
                    qa_[i] = *(const float4*)&Qc[(ty * 4 + i) * QSTR + dd];
#pragma unroll
                for (int j = 0; j < 4; ++j)
                    kb_[j] = *(const float4*)&Kc[(tx * 4 + j) * QSTR + dd];
#pragma unroll
                for (int i = 0; i < 4; ++i)
#pragma unroll
                    for (int j = 0; j < 4; ++j) {
                        s[i][j] = fmaf(qa_[i].x, kb_[j].x, s[i][j]);
                        s[i][j] = fmaf(qa_[i].y, kb_[j].y, s[i][j]);
                        s[i][j] = fmaf(qa_[i].z, kb_[j].z, s[i][j]);
                        s[i][j] = fmaf(qa_[i].w, kb_[j].w, s[i][j]);
                    }
            }
            __syncthreads();
        }

        // scale + causal mask + online softmax update
        const bool diag = (kt == qb);
#pragma unroll
        for (int i = 0; i < 4; ++i) {
            const int r = ty * 4 + i;
            float rowmax = -3e38f;
#pragma unroll
            for (int j = 0; j < 4; ++j) {
                const int c = tx * 4 + j;
                float v = s[i][j] * SCALE_QK;
                if (diag && c > r) v = -3e38f;
                s[i][j] = v;
                rowmax = fmaxf(rowmax, v);
            }
            rowmax = fmaxf(rowmax, __shfl_xor(rowmax, 1, 64));
            rowmax = fmaxf(rowmax, __shfl_xor(rowmax, 2, 64));
            rowmax = fmaxf(rowmax, __shfl_xor(rowmax, 4, 64));
            rowmax = fmaxf(rowmax, __shfl_xor(rowmax, 8, 64));
            const float mnew  = fmaxf(mrow[i], rowmax);
            const float alpha = __expf(mrow[i] - mnew);
            mrow[i] = mnew;
            float ps = 0.f;
#pragma unroll
            for (int j = 0; j < 4; ++j) {
                s[i][j] = __expf(s[i][j] - mnew);
                ps += s[i][j];
            }
            ps += __shfl_xor(ps, 1, 64);
            ps += __shfl_xor(ps, 2, 64);
            ps += __shfl_xor(ps, 4, 64);
            ps += __shfl_xor(ps, 8, 64);
            lsum[i] = lsum[i] * alpha + ps;
#pragma unroll
            for (int j = 0; j < 8; ++j) o[i][j] *= alpha;
        }

        // write P tile
#pragma unroll
        for (int i = 0; i < 4; ++i) {
            float4 pv = make_float4(s[i][0], s[i][1], s[i][2], s[i][3]);
            *(float4*)&Ps[(ty * 4 + i) * QSTR + tx * 4] = pv;
        }
        // stage V tile (overlays Qc/Kc; safe: last dc compute ended with syncthreads)
        {
            const float* vp = kvup + ((size_t)b * 1024 + ct + lr) * 16384 + n * 256 + 128;
#pragma unroll
            for (int k = 0; k < 8; ++k) {
                const int c = c0 + 16 * k;
                *(float4*)&Vs[lr * VSTR + c] = *(const float4*)(vp + c);
            }
        }
        __syncthreads();
        // PV accumulate
#pragma unroll 4
        for (int c = 0; c < TK; ++c) {
            float4 v0 = *(const float4*)&Vs[c * VSTR + tx * 8];
            float4 v1 = *(const float4*)&Vs[c * VSTR + tx * 8 + 4];
            float vv[8] = {v0.x, v0.y, v0.z, v0.w, v1.x, v1.y, v1.z, v1.w};
#pragma unroll
            for (int i = 0; i < 4; ++i) {
                const float p = Ps[(ty * 4 + i) * QSTR + c];
#pragma unroll
                for (int j = 0; j < 8; ++j) o[i][j] = fmaf(p, vv[j], o[i][j]);
            }
        }
        __syncthreads();
    }

    // epilogue: normalize and store [row][n*128 + dv]
#pragma unroll
    for (int i = 0; i < 4; ++i) {
        const float inv = 1.0f / lsum[i];
        float* op = attno + (qrow0 + ty * 4 + i) * 8192 + n * 128 + tx * 8;
        float4 r0 = make_float4(o[i][0] * inv, o[i][1] * inv, o[i][2] * inv, o[i][3] * inv);
        float4 r1 = make_float4(o[i][4] * inv, o[i][5] * inv, o[i][6] * inv, o[i][7] * inv);
        *(float4*)op = r0;
        *(float4*)(op + 4) = r1;
    }
}

// ---------------------------------------------------------------------------
extern "C" void kernel_launch(void* const* d_in, const int* in_sizes, int n_in,
                              void* d_out, int out_size, void* d_ws, size_t ws_size,
                              hipStream_t stream)
{
    const float* hidden    = (const float*)d_in[0];
    const int*   pos       = (const int*)d_in[1];
    const float* cosT      = (const float*)d_in[2];
    const float* sinT      = (const float*)d_in[3];
    const float* q_a_w     = (const float*)d_in[4];
    const float* q_a_ln_w  = (const float*)d_in[5];
    const float* q_b_w     = (const float*)d_in[6];
    const float* kv_a_w    = (const float*)d_in[7];
    const float* kv_a_ln_w = (const float*)d_in[8];
    const float* kv_b_w    = (const float*)d_in[9];
    const float* o_w       = (const float*)d_in[10];
    float* out = (float*)d_out;

    float* ws    = (float*)d_ws;
    float* qa    = ws;                                // 2048*1536
    float* qbuf  = qa   + (size_t)2048 * 1536;        // 2048*12288
    float* kva   = qbuf + (size_t)2048 * 12288;       // 2048*576
    float* ckv   = kva  + (size_t)2048 * 576;         // 2048*512
    float* kpe   = ckv  + (size_t)2048 * 512;         // 2048*64
    float* kvup  = kpe  + (size_t)2048 * 64;          // 2048*16384
    float* attno = kvup + (size_t)2048 * 16384;       // 2048*8192
    // total ws use: 81,002,496 floats = 324 MB

    // 1. q_a = hidden @ q_a_w^T            [2048,1536]
    gemm_abt<<<dim3(12, 16), 256, 0, stream>>>(hidden, q_a_w, qa, 2048, 1536, 4096);
    // 2. rmsnorm(q_a) in place
    rmsnorm_inplace<<<2048, 256, 0, stream>>>(qa, q_a_ln_w, 1536);
    // 3. q = q_a_n @ q_b_w^T               [2048,12288]
    gemm_abt<<<dim3(96, 16), 256, 0, stream>>>(qa, q_b_w, qbuf, 2048, 12288, 1536);
    // 4. kv_a = hidden @ kv_a_w^T          [2048,576]
    gemm_abt<<<dim3(5, 16), 256, 0, stream>>>(hidden, kv_a_w, kva, 2048, 576, 4096);
    // 5. ckv = rmsnorm(kv_a[:,:512]); k_pe = rope(kv_a[:,512:])
    kv_norm_rope<<<2048, 256, 0, stream>>>(kva, kv_a_ln_w, pos, cosT, sinT, ckv, kpe);
    // 6. rope(q_pe) in place
    qpe_rope<<<32768, 256, 0, stream>>>(qbuf, pos, cosT, sinT);
    // 7. kvup = ckv @ kv_b_w^T             [2048,16384]  (per-head K_nope||V)
    gemm_abt<<<dim3(128, 16), 256, 0, stream>>>(ckv, kv_b_w, kvup, 2048, 16384, 512);
    // 8. flash attention -> attno          [2048,8192]
    attn_kernel<<<dim3(16, 64, 2), 256, 0, stream>>>(qbuf, kvup, kpe, attno);
    // 9. out = attno @ o_w^T               [2048,4096]
    gemm_abt<<<dim3(32, 16), 256, 0, stream>>>(attno, o_w, out, 2048, 4096, 8192);
}

// Round 3
// 1139.835 us; speedup vs baseline: 6.8227x; 6.8227x over previous
//
#include <hip/hip_runtime.h>
#include <hip/hip_bf16.h>
#include <math.h>

// MLA prefill, bf16 MFMA version.
// B=2 S=1024 H=4096 N=64 NOPE=128 ROPE=64 V=128 KV_LORA=512 Q_LORA=1536 QK=192

#define SCALE_QK 0.07216878364870322f  // 192^-0.5

typedef short bf16x8 __attribute__((ext_vector_type(8)));
typedef float f32x4  __attribute__((ext_vector_type(4)));

// ---------------------------------------------------------------------------
// cast fp32 -> bf16 (n % 8 == 0)
// ---------------------------------------------------------------------------
__global__ __launch_bounds__(256) void cast_f32_bf16(
    const float* __restrict__ src, __hip_bfloat16* __restrict__ dst, long n)
{
    long i = ((long)blockIdx.x * 256 + threadIdx.x) * 8;
    if (i >= n) return;
    float4 a = *(const float4*)(src + i);
    float4 b = *(const float4*)(src + i + 4);
    union { bf16x8 v; __hip_bfloat16 h[8]; } u;
    u.h[0] = __float2bfloat16(a.x); u.h[1] = __float2bfloat16(a.y);
    u.h[2] = __float2bfloat16(a.z); u.h[3] = __float2bfloat16(a.w);
    u.h[4] = __float2bfloat16(b.x); u.h[5] = __float2bfloat16(b.y);
    u.h[6] = __float2bfloat16(b.z); u.h[7] = __float2bfloat16(b.w);
    *(bf16x8*)(dst + i) = u.v;
}

// cast kv_a_w [576][4096] -> bf16 padded [640][4096], rows 576..639 = 0
__global__ __launch_bounds__(256) void cast_pad_kvaw(
    const float* __restrict__ src, __hip_bfloat16* __restrict__ dst)
{
    long i = ((long)blockIdx.x * 256 + threadIdx.x) * 8;
    if (i >= 640L * 4096) return;
    const int row = (int)(i >> 12);
    union { bf16x8 v; __hip_bfloat16 h[8]; } u;
    if (row < 576) {
        float4 a = *(const float4*)(src + i);
        float4 b = *(const float4*)(src + i + 4);
        u.h[0] = __float2bfloat16(a.x); u.h[1] = __float2bfloat16(a.y);
        u.h[2] = __float2bfloat16(a.z); u.h[3] = __float2bfloat16(a.w);
        u.h[4] = __float2bfloat16(b.x); u.h[5] = __float2bfloat16(b.y);
        u.h[6] = __float2bfloat16(b.z); u.h[7] = __float2bfloat16(b.w);
    } else {
        for (int j = 0; j < 8; ++j) u.h[j] = __float2bfloat16(0.f);
    }
    *(bf16x8*)(dst + i) = u.v;
}

// ---------------------------------------------------------------------------
// GEMM bf16: C[M,N] = A[M,K] @ B[N,K]^T, MFMA 16x16x32, tile 128x128, BK=32.
// M%128==0, N%128==0, K%32==0. OUT_BF16: 1 -> bf16 C, 0 -> fp32 C.
// m97 structure: global_load_lds width-16 staging, 2 barriers per K-step.
// ---------------------------------------------------------------------------
template<int OUT_BF16>
__global__ __launch_bounds__(256) void gemm_bf16(
    const __hip_bfloat16* __restrict__ A, const __hip_bfloat16* __restrict__ B,
    void* __restrict__ Cv, int M, int N, int K)
{
    __shared__ __hip_bfloat16 Asm[128 * 32];   // rows of 32 bf16 = 64B, linear
    __shared__ __hip_bfloat16 Bsm[128 * 32];
    const int t  = threadIdx.x;
    const int w  = t >> 6, l = t & 63;
    const int wr = w >> 1, wc = w & 1;          // wave -> 64x64 quadrant
    const int lr = l & 15, g = l >> 4;
    const int m0 = blockIdx.y * 128, n0 = blockIdx.x * 128;
    const int srow = l >> 2;                    // 0..15 staging row in 16-row group
    const int schk = l & 3;                     // 16B chunk (8 bf16)

    f32x4 acc[4][4] = {};

    for (int k0 = 0; k0 < K; k0 += 32) {
#pragma unroll
        for (int i = 0; i < 2; ++i) {
            const int ia = w * 2 + i;           // 16-row group 0..7
            const __hip_bfloat16* ga = A + (size_t)(m0 + ia * 16 + srow) * K + k0 + schk * 8;
            __builtin_amdgcn_global_load_lds(
                (const __attribute__((address_space(1))) void*)ga,
                (__attribute__((address_space(3))) void*)(Asm + ia * 512), 16, 0, 0);
            const __hip_bfloat16* gb = B + (size_t)(n0 + ia * 16 + srow) * K + k0 + schk * 8;
            __builtin_amdgcn_global_load_lds(
                (const __attribute__((address_space(1))) void*)gb,
                (__attribute__((address_space(3))) void*)(Bsm + ia * 512), 16, 0, 0);
        }
        __syncthreads();
        bf16x8 af[4], bfr[4];
#pragma unroll
        for (int fi = 0; fi < 4; ++fi)
            af[fi] = *(const bf16x8*)(Asm + (wr * 64 + fi * 16 + lr) * 32 + g * 8);
#pragma unroll
        for (int fj = 0; fj < 4; ++fj)
            bfr[fj] = *(const bf16x8*)(Bsm + (wc * 64 + fj * 16 + lr) * 32 + g * 8);
#pragma unroll
        for (int fi = 0; fi < 4; ++fi)
#pragma unroll
            for (int fj = 0; fj < 4; ++fj)
                acc[fi][fj] = __builtin_amdgcn_mfma_f32_16x16x32_bf16(
                    af[fi], bfr[fj], acc[fi][fj], 0, 0, 0);
        __syncthreads();
    }

    // epilogue: D row = g*4 + r, col = lr  (verified layout)
#pragma unroll
    for (int fi = 0; fi < 4; ++fi)
#pragma unroll
        for (int fj = 0; fj < 4; ++fj) {
            const int col = n0 + wc * 64 + fj * 16 + lr;
#pragma unroll
            for (int r = 0; r < 4; ++r) {
                const size_t row = (size_t)(m0 + wr * 64 + fi * 16 + g * 4 + r);
                if (OUT_BF16)
                    ((__hip_bfloat16*)Cv)[row * N + col] = __float2bfloat16(acc[fi][fj][r]);
                else
                    ((float*)Cv)[row * N + col] = acc[fi][fj][r];
            }
        }
}

// ---------------------------------------------------------------------------
// rmsnorm over rows of 1536 fp32 -> bf16 out
// ---------------------------------------------------------------------------
__global__ __launch_bounds__(256) void rmsnorm_qa(
    const float* __restrict__ x, const float* __restrict__ w,
    __hip_bfloat16* __restrict__ o)
{
    __shared__ float red[4];
    const int row = blockIdx.x;
    const float* xr = x + (size_t)row * 1536;
    float ss = 0.f;
#pragma unroll
    for (int i = threadIdx.x; i < 1536; i += 256) { float v = xr[i]; ss = fmaf(v, v, ss); }
#pragma unroll
    for (int off = 1; off < 64; off <<= 1) ss += __shfl_xor(ss, off, 64);
    const int lane = threadIdx.x & 63, wid = threadIdx.x >> 6;
    if (lane == 0) red[wid] = ss;
    __syncthreads();
    ss = red[0] + red[1] + red[2] + red[3];
    const float r = rsqrtf(ss / 1536.f + 1e-6f);
#pragma unroll
    for (int i = threadIdx.x; i < 1536; i += 256)
        o[(size_t)row * 1536 + i] = __float2bfloat16(xr[i] * r * w[i]);
}

// ---------------------------------------------------------------------------
// kv_a [2048][640] fp32 -> ckv bf16 [2048][512] (rmsnorm) + kpe bf16 [2048][64] (rope)
// ---------------------------------------------------------------------------
__global__ __launch_bounds__(256) void kv_norm_rope(
    const float* __restrict__ kva, const float* __restrict__ w,
    const int* __restrict__ pos, const float* __restrict__ cosT,
    const float* __restrict__ sinT, __hip_bfloat16* __restrict__ ckv,
    __hip_bfloat16* __restrict__ kpe)
{
    __shared__ float red[4];
    const int row = blockIdx.x;
    const float* xr = kva + (size_t)row * 640;
    float ss = 0.f;
#pragma unroll
    for (int i = threadIdx.x; i < 512; i += 256) { float v = xr[i]; ss = fmaf(v, v, ss); }
#pragma unroll
    for (int off = 1; off < 64; off <<= 1) ss += __shfl_xor(ss, off, 64);
    const int lane = threadIdx.x & 63, wid = threadIdx.x >> 6;
    if (lane == 0) red[wid] = ss;
    __syncthreads();
    ss = red[0] + red[1] + red[2] + red[3];
    const float r = rsqrtf(ss / 512.f + 1e-6f);
#pragma unroll
    for (int i = threadIdx.x; i < 512; i += 256)
        ckv[(size_t)row * 512 + i] = __float2bfloat16(xr[i] * r * w[i]);
    if (threadIdx.x < 64) {
        const int d = threadIdx.x;
        const int p = pos[row];
        const float xd = xr[512 + d];
        const float xp = xr[512 + (d ^ 32)];
        const float rot = (d < 32) ? -xp : xp;
        kpe[(size_t)row * 64 + d] = __float2bfloat16(xd * cosT[p * 64 + d] + rot * sinT[p * 64 + d]);
    }
}

// ---------------------------------------------------------------------------
// RoPE on q_pe in place, bf16. q [2048][64 heads][192], pe dims 128..191.
// d and d^32 in same wave; loads precede store -> race-free.
// ---------------------------------------------------------------------------
__global__ __launch_bounds__(256) void qpe_rope_bf(
    __hip_bfloat16* __restrict__ q, const int* __restrict__ pos,
    const float* __restrict__ cosT, const float* __restrict__ sinT)
{
    const int idx = blockIdx.x * 256 + threadIdx.x;
    const int d = idx & 63;
    const int n = (idx >> 6) & 63;
    const int row = idx >> 12;
    const int p = pos[row];
    __hip_bfloat16* qp = q + (size_t)row * 12288 + n * 192 + 128;
    const float xd = __bfloat162float(qp[d]);
    const float xp = __bfloat162float(qp[d ^ 32]);
    const float rot = (d < 32) ? -xp : xp;
    qp[d] = __float2bfloat16(xd * cosT[p * 64 + d] + rot * sinT[p * 64 + d]);
}

// ---------------------------------------------------------------------------
// Flash attention, bf16 MFMA. Block = (qb, head n, batch b), 256 thr = 4 waves.
// Wave w owns q rows [w*16, w*16+16). Per kt (64 keys):
//   QK^T: 6 ks x 4 t-frags MFMA; softmax in-register (row = g*4+r, col = ft*16+lr);
//   P -> wave-private LDS (stride 72); PV: 2 ks x 8 v-frags MFMA from V^T LDS.
// V^T staged swizzled: byte(v,t) = v*144 + ((2t) ^ (((v>>3)&7)<<4)) -> ~2-way banks.
// K staged at stride 200 (8-bank-class floor for b128 frag reads).
// LDS: K 25600 + V^T 18432 + P 9216 = 53248 B -> 3 blocks/CU.
// ---------------------------------------------------------------------------
__global__ __launch_bounds__(256) void attn_mfma(
    const __hip_bfloat16* __restrict__ q,     // [2048][12288]
    const __hip_bfloat16* __restrict__ kvup,  // [2048][16384] per-head K||V
    const __hip_bfloat16* __restrict__ kpe,   // [2048][64]
    __hip_bfloat16* __restrict__ attno)       // [2048][8192]
{
    __shared__ __hip_bfloat16 Ksm[64 * 200];
    __shared__ unsigned char  Vsm[128 * 144];
    __shared__ __hip_bfloat16 Psm[4 * 16 * 72];

    const int t  = threadIdx.x;
    const int w  = t >> 6, l = t & 63;
    const int lr = l & 15, g = l >> 4;
    const int qb = blockIdx.x, n = blockIdx.y, b = blockIdx.z;
    const int qs = qb * 64;
    const size_t rowQ = (size_t)b * 1024 + qs + w * 16 + lr;

    // Q fragments: A-frag row = lr, k = ks*32 + g*8 .. +7 (contiguous)
    bf16x8 qf[6];
#pragma unroll
    for (int ks = 0; ks < 6; ++ks)
        qf[ks] = *(const bf16x8*)(q + rowQ * 12288 + n * 192 + ks * 32 + g * 8);

    f32x4 oacc[8] = {};
    float m_[4], l_[4];
#pragma unroll
    for (int r = 0; r < 4; ++r) { m_[r] = -INFINITY; l_[r] = 0.f; }

    __hip_bfloat16* Pw = Psm + w * 16 * 72;

    for (int kt = 0; kt <= qb; ++kt) {
        const int ct = kt * 64;
        // ---- stage K tile (64 x 192): waves cover chunk ranges ----
        {
            const int tr  = t & 63;
            const int chb = (t >> 6) * 6;
            const size_t grow = (size_t)b * 1024 + ct + tr;
#pragma unroll
            for (int i = 0; i < 6; ++i) {
                const int ch = chb + i;
                bf16x8 v;
                if (ch < 16) v = *(const bf16x8*)(kvup + grow * 16384 + n * 256 + ch * 8);
                else         v = *(const bf16x8*)(kpe + grow * 64 + (ch - 16) * 8);
                *(bf16x8*)(Ksm + tr * 200 + ch * 8) = v;
            }
        }
        // ---- stage V^T swizzled ----
        {
#pragma unroll
            for (int i = 0; i < 4; ++i) {
                const int cc  = t + 256 * i;        // 0..1023
                const int tr  = cc >> 4;
                const int v0  = (cc & 15) * 8;
                const int key = cc & 7;             // ((v>>3)&7) for this chunk
                const size_t grow = (size_t)b * 1024 + ct + tr;
                union { bf16x8 v; __hip_bfloat16 h[8]; } u;
                u.v = *(const bf16x8*)(kvup + grow * 16384 + n * 256 + 128 + v0);
                const int tb = (2 * tr) ^ (key << 4);
#pragma unroll
                for (int j = 0; j < 8; ++j)
                    *(__hip_bfloat16*)(Vsm + (size_t)(v0 + j) * 144 + tb) = u.h[j];
            }
        }
        __syncthreads();

        // ---- QK^T: D row(q) = g*4+r, col(t) = ft*16+lr ----
        f32x4 sacc[4] = {};
#pragma unroll
        for (int ks = 0; ks < 6; ++ks)
#pragma unroll
            for (int ft = 0; ft < 4; ++ft) {
                bf16x8 kf = *(const bf16x8*)(Ksm + (ft * 16 + lr) * 200 + ks * 32 + g * 8);
                sacc[ft] = __builtin_amdgcn_mfma_f32_16x16x32_bf16(qf[ks], kf, sacc[ft], 0, 0, 0);
            }

        // ---- online softmax ----
        const bool diag = (kt == qb);
#pragma unroll
        for (int r = 0; r < 4; ++r) {
            const int qg = qs + w * 16 + g * 4 + r;
            float pv[4];
            float rmax = -3e38f;
#pragma unroll
            for (int ft = 0; ft < 4; ++ft) {
                float v = sacc[ft][r] * SCALE_QK;
                if (diag && (ct + ft * 16 + lr) > qg) v = -3e38f;
                pv[ft] = v;
                rmax = fmaxf(rmax, v);
            }
            rmax = fmaxf(rmax, __shfl_xor(rmax, 1, 64));
            rmax = fmaxf(rmax, __shfl_xor(rmax, 2, 64));
            rmax = fmaxf(rmax, __shfl_xor(rmax, 4, 64));
            rmax = fmaxf(rmax, __shfl_xor(rmax, 8, 64));
            const float mnew  = fmaxf(m_[r], rmax);
            const float alpha = __expf(m_[r] - mnew);
            m_[r] = mnew;
            float ps = 0.f;
#pragma unroll
            for (int ft = 0; ft < 4; ++ft) {
                const float e = __expf(pv[ft] - mnew);
                pv[ft] = e;
                ps += e;
            }
            ps += __shfl_xor(ps, 1, 64);
            ps += __shfl_xor(ps, 2, 64);
            ps += __shfl_xor(ps, 4, 64);
            ps += __shfl_xor(ps, 8, 64);
            l_[r] = l_[r] * alpha + ps;
#pragma unroll
            for (int fj = 0; fj < 8; ++fj) oacc[fj][r] *= alpha;
#pragma unroll
            for (int ft = 0; ft < 4; ++ft)
                Pw[(g * 4 + r) * 72 + ft * 16 + lr] = __float2bfloat16(pv[ft]);
        }

        // ---- PV: A = P (row=lr, k contiguous), B = V^T frags ----
#pragma unroll
        for (int s = 0; s < 2; ++s) {
            bf16x8 pa = *(const bf16x8*)(Pw + lr * 72 + s * 32 + g * 8);
#pragma unroll
            for (int fj = 0; fj < 8; ++fj) {
                const int v = fj * 16 + lr;
                const int chunk = (((4 * s + g) ^ ((v >> 3) & 7)) << 4);
                bf16x8 bv = *(const bf16x8*)(Vsm + (size_t)v * 144 + chunk);
                oacc[fj] = __builtin_amdgcn_mfma_f32_16x16x32_bf16(pa, bv, oacc[fj], 0, 0, 0);
            }
        }
        __syncthreads();
    }

    // epilogue
#pragma unroll
    for (int r = 0; r < 4; ++r) {
        const float inv = 1.f / l_[r];
        const size_t orow = (size_t)b * 1024 + qs + w * 16 + g * 4 + r;
#pragma unroll
        for (int fj = 0; fj < 8; ++fj)
            attno[orow * 8192 + n * 128 + fj * 16 + lr] = __float2bfloat16(oacc[fj][r] * inv);
    }
}

// ---------------------------------------------------------------------------
extern "C" void kernel_launch(void* const* d_in, const int* in_sizes, int n_in,
                              void* d_out, int out_size, void* d_ws, size_t ws_size,
                              hipStream_t stream)
{
    const float* hidden    = (const float*)d_in[0];
    const int*   pos       = (const int*)d_in[1];
    const float* cosT      = (const float*)d_in[2];
    const float* sinT      = (const float*)d_in[3];
    const float* q_a_w     = (const float*)d_in[4];
    const float* q_a_ln_w  = (const float*)d_in[5];
    const float* q_b_w     = (const float*)d_in[6];
    const float* kv_a_w    = (const float*)d_in[7];
    const float* kv_a_ln_w = (const float*)d_in[8];
    const float* kv_b_w    = (const float*)d_in[9];
    const float* o_w       = (const float*)d_in[10];
    float* out = (float*)d_out;

    char* p = (char*)d_ws;
    __hip_bfloat16* hbf      = (__hip_bfloat16*)p; p += 2048L * 4096 * 2;
    __hip_bfloat16* wbf      = (__hip_bfloat16*)p; p += 67108864;        // max weight (o_w)
    float*          qa_f32   = (float*)p;          p += 2048L * 1536 * 4;
    __hip_bfloat16* qa_bf    = (__hip_bfloat16*)p; p += 2048L * 1536 * 2;
    __hip_bfloat16* qbuf_bf  = (__hip_bfloat16*)p; p += 2048L * 12288 * 2;
    float*          kva_f32  = (float*)p;          p += 2048L * 640 * 4;
    __hip_bfloat16* ckv_bf   = (__hip_bfloat16*)p; p += 2048L * 512 * 2;
    __hip_bfloat16* kpe_bf   = (__hip_bfloat16*)p; p += 2048L * 64 * 2;
    __hip_bfloat16* kvup_bf  = (__hip_bfloat16*)p; p += 2048L * 16384 * 2;
    __hip_bfloat16* attno_bf = (__hip_bfloat16*)p; p += 2048L * 8192 * 2;
    // total ws use ~= 249 MiB

    auto nb8 = [](long n) { return (int)((n / 8 + 255) / 256); };

    // hidden -> bf16
    cast_f32_bf16<<<nb8(2048L * 4096), 256, 0, stream>>>(hidden, hbf, 2048L * 4096);

    // q_a = hidden @ q_a_w^T (fp32 out for rmsnorm)
    cast_f32_bf16<<<nb8(1536L * 4096), 256, 0, stream>>>(q_a_w, wbf, 1536L * 4096);
    gemm_bf16<0><<<dim3(12, 16), 256, 0, stream>>>(hbf, wbf, qa_f32, 2048, 1536, 4096);
    rmsnorm_qa<<<2048, 256, 0, stream>>>(qa_f32, q_a_ln_w, qa_bf);

    // q = rms(q_a) @ q_b_w^T (bf16 out)
    cast_f32_bf16<<<nb8(12288L * 1536), 256, 0, stream>>>(q_b_w, wbf, 12288L * 1536);
    gemm_bf16<1><<<dim3(96, 16), 256, 0, stream>>>(qa_bf, wbf, qbuf_bf, 2048, 12288, 1536);

    // kv_a = hidden @ kv_a_w^T (N padded 576->640, fp32 out)
    cast_pad_kvaw<<<nb8(640L * 4096), 256, 0, stream>>>(kv_a_w, wbf);
    gemm_bf16<0><<<dim3(5, 16), 256, 0, stream>>>(hbf, wbf, kva_f32, 2048, 640, 4096);
    kv_norm_rope<<<2048, 256, 0, stream>>>(kva_f32, kv_a_ln_w, pos, cosT, sinT, ckv_bf, kpe_bf);

    // rope(q_pe) in place (bf16)
    qpe_rope_bf<<<32768, 256, 0, stream>>>(qbuf_bf, pos, cosT, sinT);

    // kvup = ckv @ kv_b_w^T (bf16 out): per-head K_nope||V
    cast_f32_bf16<<<nb8(16384L * 512), 256, 0, stream>>>(kv_b_w, wbf, 16384L * 512);
    gemm_bf16<1><<<dim3(128, 16), 256, 0, stream>>>(ckv_bf, wbf, kvup_bf, 2048, 16384, 512);

    // flash attention
    attn_mfma<<<dim3(16, 64, 2), 256, 0, stream>>>(qbuf_bf, kvup_bf, kpe_bf, attno_bf);

    // out = attno @ o_w^T (fp32 out)
    cast_f32_bf16<<<nb8(4096L * 8192), 256, 0, stream>>>(o_w, wbf, 4096L * 8192);
    gemm_bf16<0><<<dim3(32, 16), 256, 0, stream>>>(attno_bf, wbf, out, 2048, 4096, 8192);
}